// Round 6
// baseline (439.319 us; speedup 1.0000x reference)
//
#include <hip/hip_runtime.h>
#include <stdint.h>
#include <stddef.h>

// Problem constants
#define T_ 512
#define B_ 256
#define IN_ 292
#define H_ 128
#define G4_ 512     // 4*H
#define TB_ 131072  // T_*B_
#define LCH 32      // time-chunk length for the segment scan
#define NCH 16      // number of chunks (T_/LCH)
#define KP_ 320     // K padded to 10*32

typedef short bf16x8 __attribute__((ext_vector_type(8)));
typedef float f32x4 __attribute__((ext_vector_type(4)));
typedef unsigned int u32t;

__device__ __forceinline__ unsigned short f2bf(float f) {
  unsigned u = __float_as_uint(f);
  u += 0x7FFFu + ((u >> 16) & 1u);   // RTNE
  return (unsigned short)(u >> 16);
}
__device__ __forceinline__ float bf2f(unsigned short s) {
  return __uint_as_float(((unsigned)s) << 16);
}
// two fp32 -> packed bf16 pair (round-half-up). 1.5 VALU ops/elem.
__device__ __forceinline__ unsigned bfpack2(float a, float b) {
  unsigned ua = __float_as_uint(a) + 0x8000u;
  unsigned ub = __float_as_uint(b) + 0x8000u;
  return __builtin_amdgcn_perm(ub, ua, 0x07060302u);  // [ub.hi16 : ua.hi16]
}
__device__ __forceinline__ float sigf(float x) {
  return __builtin_amdgcn_rcpf(1.0f + __expf(-x));
}
__device__ __forceinline__ float tanhf_(float x) {
  return 1.0f - 2.0f * __builtin_amdgcn_rcpf(__expf(2.0f * x) + 1.0f);
}
// LDS-only barrier: lgkmcnt(0)+s_barrier, leaves global loads/stores in flight.
__device__ __forceinline__ void barrier_lds() {
  asm volatile("s_waitcnt lgkmcnt(0)\n\ts_barrier" ::: "memory");
}
// async global->LDS, 16B per lane; LDS dst = wave-uniform base + lane*16.
__device__ __forceinline__ void gload_lds16(const void* g, void* l) {
  __builtin_amdgcn_global_load_lds(
      (const __attribute__((address_space(1))) u32t*)g,
      (__attribute__((address_space(3))) u32t*)l, 16, 0, 0);
}
// load one lane's 4 cell-quads (32 B contiguous): pr[r] = {i,f,g,o} of cell r.
__device__ __forceinline__ void load_pr(const unsigned short* p, ushort4* pr) {
  union { uint4 v; ushort4 s[2]; } a, b;
  a.v = *(const uint4*)p;
  b.v = *(const uint4*)(p + 8);
  pr[0] = a.s[0]; pr[1] = a.s[1]; pr[2] = b.s[0]; pr[3] = b.s[1];
}

// ---------------------------------------------------------------------------
// K0w: W_ih fp32 [512][292] -> Wb2 bf16 [512][320], ROW-REORDERED so that
// row jj = W_ih row (jj&3)*128 + (jj>>2)   (jj = cell*4 + gate).
// Also emits reordered bias2[jj] (fp32).
// ---------------------------------------------------------------------------
__global__ __launch_bounds__(256) void k0w_cvt(
    const float* __restrict__ Wih, const float* __restrict__ bih,
    const float* __restrict__ bhh, unsigned short* __restrict__ Wb,
    float* __restrict__ bias2) {
  const int g = blockIdx.x * 256 + threadIdx.x;
  const int jj = g / 40, s = g % 40;
  const int src = (jj & 3) * 128 + (jj >> 2);
  if (g < 512) {
    const int sb = (g & 3) * 128 + (g >> 2);
    bias2[g] = bih[sb] + bhh[sb];
  }
  float4 a = {0.f, 0.f, 0.f, 0.f}, b = {0.f, 0.f, 0.f, 0.f};
  const float* p = Wih + (size_t)src * IN_ + 8 * s;
  if (s < 36) { a = *(const float4*)p; b = *(const float4*)(p + 4); }
  else if (s == 36) { a = *(const float4*)p; }  // floats 288..291
  uint4 o;
  o.x = bfpack2(a.x, a.y); o.y = bfpack2(a.z, a.w);
  o.z = bfpack2(b.x, b.y); o.w = bfpack2(b.z, b.w);
  *(uint4*)&Wb[(size_t)jj * KP_ + 8 * s] = o;
}

// ---------------------------------------------------------------------------
// K1 v3: pre2[m][jj] (bf16) = x @ Wb2^T + bias2, jj = cell*4+gate.
// Grid 1024 (m-tile 128), 512 thr, wave w owns jj [64w,64w+64) x 128 m.
//  - x staged fp32 via global_load_lds width-16 into a 3-buffer LDS ring
//    (16 KB/tile), issue distance 2; DMA queue (not VGPRs) holds the
//    outstanding bytes -> HBM BW not latency-capped.
//  - LDS tile is row-major [128][32] fp32 (DMA forces lane-contiguous dst);
//    16-way column bank conflicts killed by XOR-swizzling the DMA SOURCE:
//    LDS slot s of row r holds global chunk (s ^ (r&7)). Readers: 2-way=free.
//  - Consume gate: asm "s_waitcnt vmcnt(N) lgkmcnt(0); s_barrier" with exact
//    N = #vm-ops issued after the needed DMA (6 steady / 4 at it=7 / lgkm at
//    it=8). Extra compiler vm-ops only make the wait stricter (fail-safe).
//  - W frags direct global->reg (Wb2 = 320 KB, L2-hot), prefetch dist 2.
//  - k-tail (floats 288..291) staged once to LDS, used in an extra iter.
//  - Epilogue ms-outer so the 4 stores covering one 128 B line issue
//    back-to-back (write-amp fix; r5 showed 1.45x).
// ---------------------------------------------------------------------------
__global__ __launch_bounds__(512, 2) void k1_pregemm(
    const float* __restrict__ x, const unsigned short* __restrict__ Wb,
    const float* __restrict__ bias2, unsigned short* __restrict__ pre2) {
  __shared__ float xr[3][128 * 32];   // 48 KB ring, XOR-swizzled chunks
  __shared__ float xtail[128 * 4];    // floats 288..291 per row

  const int m0 = blockIdx.x * 128;
  const int tid = threadIdx.x;
  const int w = tid >> 6;
  const int lane = tid & 63;
  const int l15 = lane & 15;
  const int q = lane >> 4;

  // ---- one-time: k-tail floats 288..291 per row -> LDS ----
  if (tid < 128) {
    float4 t = *(const float4*)(x + (size_t)(m0 + tid) * IN_ + 288);
    *(float4*)&xtail[tid * 4] = t;
  }

  // ---- W fragment stages (prefetch distance 2) ----
  bf16x8 af_c[4], af_n[4];
#pragma unroll
  for (int s = 0; s < 4; s++) {
    af_c[s] = *(const bf16x8*)&Wb[(size_t)(w * 64 + 16 * s + l15) * KP_ + q * 8];
    af_n[s] = *(const bf16x8*)&Wb[(size_t)(w * 64 + 16 * s + l15) * KP_ + 32 + q * 8];
  }

  // ---- DMA one k-tile (32 floats x 128 rows) into ring buf tile%3 ----
  // wave w stages rows [16w,16w+16); lane chunk c = lane + 64j;
  // row = 16w + (c>>3), slot = c&7, source chunk = slot ^ (row&7).
#define DMA_TILE(tile)                                                        \
  {                                                                           \
    const int _buf = (tile) % 3;                                              \
    _Pragma("unroll")                                                         \
    for (int _j = 0; _j < 2; _j++) {                                          \
      const int _c = lane + 64 * _j;                                          \
      const int _row = 16 * w + (_c >> 3);                                    \
      const int _slot = _c & 7;                                               \
      const float* _src = x + (size_t)(m0 + _row) * IN_ + (tile) * 32 +       \
                          ((_slot ^ (_row & 7)) * 4);                         \
      gload_lds16(_src, &xr[_buf][w * 512 + _c * 4]);                         \
    }                                                                         \
  }

  f32x4 acc[4][8];
#pragma unroll
  for (int s = 0; s < 4; s++)
#pragma unroll
    for (int ms = 0; ms < 8; ms++) acc[s][ms] = (f32x4){0.f, 0.f, 0.f, 0.f};

  DMA_TILE(0)
  DMA_TILE(1)
  // preloop: full drain (once) — simple and count-proof.
  asm volatile("s_waitcnt vmcnt(0) lgkmcnt(0)\n\ts_barrier" ::: "memory");

#pragma unroll
  for (int it = 0; it < 9; it++) {
    const int buf = it % 3;
    // x B-frags from swizzled LDS: slot = chunk ^ (l15&7), 2-way free
    bf16x8 bfr[8];
#pragma unroll
    for (int ms = 0; ms < 8; ms++) {
      const int row = 16 * ms + l15;
      const int s0 = (2 * q) ^ (l15 & 7);
      const int s1 = (2 * q + 1) ^ (l15 & 7);
      float4 a = *(const float4*)&xr[buf][row * 32 + s0 * 4];
      float4 b = *(const float4*)&xr[buf][row * 32 + s1 * 4];
      uint4 v;
      v.x = bfpack2(a.x, a.y); v.y = bfpack2(a.z, a.w);
      v.z = bfpack2(b.x, b.y); v.w = bfpack2(b.z, b.w);
      bfr[ms] = *(bf16x8*)&v;
    }
#pragma unroll
    for (int s = 0; s < 4; s++)
#pragma unroll
      for (int ms = 0; ms < 8; ms++)
        acc[s][ms] = __builtin_amdgcn_mfma_f32_16x16x32_bf16(
            af_c[s], bfr[ms], acc[s][ms], 0, 0, 0);
    // rotate W stages; prefetch W(it+2) (valid through it+2==9)
#pragma unroll
    for (int s = 0; s < 4; s++) af_c[s] = af_n[s];
    if (it < 8) {
      const int kk = 32 * (it + 2);
#pragma unroll
      for (int s = 0; s < 4; s++)
        af_n[s] = *(const bf16x8*)&Wb[(size_t)(w * 64 + 16 * s + l15) * KP_ + kk + q * 8];
    }
    if (it < 7) DMA_TILE(it + 2)
    // consume gate: ensure DMA(it+1) landed; leave newer ops in flight.
    if (it < 7)
      asm volatile("s_waitcnt vmcnt(6) lgkmcnt(0)\n\ts_barrier" ::: "memory");
    else if (it == 7)
      asm volatile("s_waitcnt vmcnt(4) lgkmcnt(0)\n\ts_barrier" ::: "memory");
    else
      asm volatile("s_waitcnt lgkmcnt(0)\n\ts_barrier" ::: "memory");
  }

  // tail iter (k=288..319): q==0 lanes carry floats 288..291, rest zero
  {
    bf16x8 bfr[8];
#pragma unroll
    for (int ms = 0; ms < 8; ms++) {
      uint4 v = {0u, 0u, 0u, 0u};
      if (q == 0) {
        float4 t = *(const float4*)&xtail[(16 * ms + l15) * 4];
        v.x = bfpack2(t.x, t.y);
        v.y = bfpack2(t.z, t.w);
      }
      bfr[ms] = *(bf16x8*)&v;
    }
#pragma unroll
    for (int s = 0; s < 4; s++)
#pragma unroll
      for (int ms = 0; ms < 8; ms++)
        acc[s][ms] = __builtin_amdgcn_mfma_f32_16x16x32_bf16(
            af_c[s], bfr[ms], acc[s][ms], 0, 0, 0);
  }

  // epilogue: bias + pack + store; ms-outer so one 128 B line's 4 stores
  // issue consecutively.
  float4 bb[4];
#pragma unroll
  for (int s = 0; s < 4; s++) bb[s] = *(const float4*)&bias2[w * 64 + 16 * s + 4 * q];
#pragma unroll
  for (int ms = 0; ms < 8; ms++) {
    const int m = m0 + 16 * ms + l15;
#pragma unroll
    for (int s = 0; s < 4; s++) {
      const int jjb = w * 64 + 16 * s + 4 * q;
      uint2 st;
      st.x = bfpack2(acc[s][ms][0] + bb[s].x, acc[s][ms][1] + bb[s].y);
      st.y = bfpack2(acc[s][ms][2] + bb[s].z, acc[s][ms][3] + bb[s].w);
      *(uint2*)&pre2[((size_t)m << 9) + jjb] = st;
    }
  }
#undef DMA_TILE
}

// ---------------------------------------------------------------------------
// Segment-scan LSTM (unchanged from round 5).
// ---------------------------------------------------------------------------
__global__ __launch_bounds__(512) void k2a_chunk(
    const unsigned short* __restrict__ pre2, const float* __restrict__ Whh,
    const int* __restrict__ done, unsigned short* __restrict__ hidden,
    unsigned short* __restrict__ hfin, float* __restrict__ cfin) {
  __shared__ unsigned short hs[2][16 * 136];
  __shared__ int dns[LCH * 16];

  const int bg = blockIdx.x & 15;
  const int ck = blockIdx.x >> 4;
  const int t0 = ck * LCH;
  const int tid = threadIdx.x;
  const int w = tid >> 6;
  const int lane = tid & 63;
  const int l15 = lane & 15;
  const int q = lane >> 4;
  const int bglob = bg * 16 + l15;
  const int kcell = 16 * w + 4 * q;
  const int kq16 = kcell * 4;

  {
    const int r = tid >> 4, c = tid & 15;
    dns[tid] = done[(size_t)(t0 + r) * B_ + bg * 16 + c];
  }

  bf16x8 wf[4][4];
#pragma unroll
  for (int tI = 0; tI < 4; tI++) {
    const int jg = 16 * (w + 8 * tI) + l15;
#pragma unroll
    for (int kc = 0; kc < 4; kc++) {
      const float* p = Whh + (size_t)jg * H_ + kc * 32 + q * 8;
      float4 u0 = *(const float4*)p;
      float4 u1 = *(const float4*)(p + 4);
      bf16x8 r;
      r[0]=(short)f2bf(u0.x); r[1]=(short)f2bf(u0.y); r[2]=(short)f2bf(u0.z); r[3]=(short)f2bf(u0.w);
      r[4]=(short)f2bf(u1.x); r[5]=(short)f2bf(u1.y); r[6]=(short)f2bf(u1.z); r[7]=(short)f2bf(u1.w);
      wf[tI][kc] = r;
    }
  }

  float c_[4] = {0.f, 0.f, 0.f, 0.f};
  {
    const int b = tid >> 5, k = (tid & 31) * 4;
    *(ushort4*)&hs[0][b * 136 + k] = (ushort4){0, 0, 0, 0};
  }
  bool vld = false;
  __syncthreads();

  ushort4 pr[4], prn[4];
  load_pr(pre2 + ((size_t)t0 * B_ + bglob) * G4_ + kq16, pr);
  load_pr(pre2 + ((size_t)(t0 + 1) * B_ + bglob) * G4_ + kq16, prn);

  ushort4 hw = {0, 0, 0, 0};
#pragma unroll 1
  for (int u = 0; u < LCH; u++) {
    const int t = t0 + u;
    ushort4 pr2[4];
    const int un = (u + 2 < LCH) ? u + 2 : LCH - 1;
    load_pr(pre2 + ((size_t)(t0 + un) * B_ + bglob) * G4_ + kq16, pr2);

    const int dn = dns[u * 16 + l15];
    vld = vld || (dn != 0);

    const unsigned short* hb = hs[u & 1];
    bf16x8 hf[4];
#pragma unroll
    for (int kc = 0; kc < 4; kc++) {
      bf16x8 v = *(const bf16x8*)&hb[l15 * 136 + kc * 32 + q * 8];
      if (dn) v = (bf16x8){0, 0, 0, 0, 0, 0, 0, 0};
      hf[kc] = v;
    }

    f32x4 acc[4];
#pragma unroll
    for (int tI = 0; tI < 4; tI++) acc[tI] = (f32x4){0.f, 0.f, 0.f, 0.f};
#pragma unroll
    for (int tI = 0; tI < 4; tI++)
#pragma unroll
      for (int kc = 0; kc < 4; kc++)
        acc[tI] = __builtin_amdgcn_mfma_f32_16x16x32_bf16(
            wf[tI][kc], hf[kc], acc[tI], 0, 0, 0);

    const float m = dn ? 0.0f : 1.0f;
    float hv[4];
#pragma unroll
    for (int r = 0; r < 4; r++) {
      const float iv = acc[0][r] + bf2f(pr[r].x);
      const float fv = acc[1][r] + bf2f(pr[r].y);
      const float gv = acc[2][r] + bf2f(pr[r].z);
      const float ov = acc[3][r] + bf2f(pr[r].w);
      float cc = c_[r] * m;
      cc = sigf(fv) * cc + sigf(iv) * tanhf_(gv);
      c_[r] = cc;
      hv[r] = sigf(ov) * tanhf_(cc);
    }
    uint2 hp = {bfpack2(hv[0], hv[1]), bfpack2(hv[2], hv[3])};
    hw = *(ushort4*)&hp;
    *(uint2*)&hs[(u + 1) & 1][l15 * 136 + kcell] = hp;
    if (vld)
      *(uint2*)&hidden[((size_t)t * B_ + bglob) * H_ + kcell] = hp;
#pragma unroll
    for (int tI = 0; tI < 4; tI++) { pr[tI] = prn[tI]; prn[tI] = pr2[tI]; }
    barrier_lds();
  }

  *(ushort4*)&hfin[((size_t)ck * B_ + bglob) * H_ + kcell] = hw;
  float4 cv = {c_[0], c_[1], c_[2], c_[3]};
  *(float4*)&cfin[((size_t)ck * B_ + bglob) * H_ + kcell] = cv;
}

__global__ __launch_bounds__(512) void k2b_par(
    const unsigned short* __restrict__ pre2, const float* __restrict__ Whh,
    const float* __restrict__ h0, const float* __restrict__ c0,
    const int* __restrict__ done, unsigned short* __restrict__ hidden,
    const unsigned short* __restrict__ hfin, const float* __restrict__ cfin,
    int* __restrict__ needfix) {
  __shared__ unsigned short hs[2][16 * 136];
  __shared__ int dns[LCH * 16];

  const int bg = blockIdx.x & 15;
  const int ck = blockIdx.x >> 4;
  const int t0 = ck * LCH;
  const int tid = threadIdx.x;
  const int w = tid >> 6;
  const int lane = tid & 63;
  const int l15 = lane & 15;
  const int q = lane >> 4;
  const int bglob = bg * 16 + l15;
  const int kcell = 16 * w + 4 * q;
  const int kq16 = kcell * 4;

  {
    const int r = tid >> 4, c = tid & 15;
    dns[tid] = done[(size_t)(t0 + r) * B_ + bg * 16 + c];
  }

  bf16x8 wf[4][4];
#pragma unroll
  for (int tI = 0; tI < 4; tI++) {
    const int jg = 16 * (w + 8 * tI) + l15;
#pragma unroll
    for (int kc = 0; kc < 4; kc++) {
      const float* p = Whh + (size_t)jg * H_ + kc * 32 + q * 8;
      float4 u0 = *(const float4*)p;
      float4 u1 = *(const float4*)(p + 4);
      bf16x8 r;
      r[0]=(short)f2bf(u0.x); r[1]=(short)f2bf(u0.y); r[2]=(short)f2bf(u0.z); r[3]=(short)f2bf(u0.w);
      r[4]=(short)f2bf(u1.x); r[5]=(short)f2bf(u1.y); r[6]=(short)f2bf(u1.z); r[7]=(short)f2bf(u1.w);
      wf[tI][kc] = r;
    }
  }

  float c_[4];
  {
    const int b = tid >> 5, k = (tid & 31) * 4;
    if (ck == 0) {
      float4 hv = *(const float4*)(h0 + (size_t)(bg * 16 + b) * H_ + k);
      uint2 hp = {bfpack2(hv.x, hv.y), bfpack2(hv.z, hv.w)};
      *(uint2*)&hs[0][b * 136 + k] = hp;
      float4 cv = *(const float4*)(c0 + (size_t)bglob * H_ + kcell);
      c_[0] = cv.x; c_[1] = cv.y; c_[2] = cv.z; c_[3] = cv.w;
    } else {
      ushort4 hv = *(const ushort4*)&hfin[((size_t)(ck - 1) * B_ + bg * 16 + b) * H_ + k];
      *(ushort4*)&hs[0][b * 136 + k] = hv;
      float4 cv = *(const float4*)&cfin[((size_t)(ck - 1) * B_ + bglob) * H_ + kcell];
      c_[0] = cv.x; c_[1] = cv.y; c_[2] = cv.z; c_[3] = cv.w;
    }
  }
  int cur = 0;
  bool act = true;
  __syncthreads();

  ushort4 pr[4];
  load_pr(pre2 + ((size_t)t0 * B_ + bglob) * G4_ + kq16, pr);

#pragma unroll 1
  for (int u = 0; u < LCH; u++) {
    const int t = t0 + u;
    const int dn = dns[u * 16 + l15];
    const bool nact = act && (dn == 0);
    if (__ballot(nact) == 0ULL) { act = false; break; }
    act = nact;

    ushort4 prn[4];
    const int un = (u + 1 < LCH) ? u + 1 : LCH - 1;
    load_pr(pre2 + ((size_t)(t0 + un) * B_ + bglob) * G4_ + kq16, prn);

    const unsigned short* hb = hs[cur];
    bf16x8 hf[4];
#pragma unroll
    for (int kc = 0; kc < 4; kc++)
      hf[kc] = *(const bf16x8*)&hb[l15 * 136 + kc * 32 + q * 8];

    f32x4 acc[4];
#pragma unroll
    for (int tI = 0; tI < 4; tI++) acc[tI] = (f32x4){0.f, 0.f, 0.f, 0.f};
#pragma unroll
    for (int tI = 0; tI < 4; tI++)
#pragma unroll
      for (int kc = 0; kc < 4; kc++)
        acc[tI] = __builtin_amdgcn_mfma_f32_16x16x32_bf16(
            wf[tI][kc], hf[kc], acc[tI], 0, 0, 0);

    float hv[4];
#pragma unroll
    for (int r = 0; r < 4; r++) {
      const float iv = acc[0][r] + bf2f(pr[r].x);
      const float fv = acc[1][r] + bf2f(pr[r].y);
      const float gv = acc[2][r] + bf2f(pr[r].z);
      const float ov = acc[3][r] + bf2f(pr[r].w);
      float cc = sigf(fv) * c_[r] + sigf(iv) * tanhf_(gv);
      c_[r] = cc;
      hv[r] = sigf(ov) * tanhf_(cc);
    }
    uint2 hp = {bfpack2(hv[0], hv[1]), bfpack2(hv[2], hv[3])};
    *(uint2*)&hs[cur ^ 1][l15 * 136 + kcell] = hp;
    if (act)
      *(uint2*)&hidden[((size_t)t * B_ + bglob) * H_ + kcell] = hp;
#pragma unroll
    for (int tI = 0; tI < 4; tI++) pr[tI] = prn[tI];
    barrier_lds();
    cur ^= 1;
  }

  if (tid == 0) needfix[blockIdx.x] = (__ballot(act) != 0ULL) ? 1 : 0;
}

// Sequential guard: exact fallback, expected to exit immediately.
__global__ __launch_bounds__(512) void k2c_guard(
    const unsigned short* __restrict__ pre2, const float* __restrict__ Whh,
    const float* __restrict__ h0, const float* __restrict__ c0,
    const int* __restrict__ done, unsigned short* __restrict__ hidden,
    const unsigned short* __restrict__ hfin, const float* __restrict__ cfin,
    const int* __restrict__ needfix) {
  const int bg = blockIdx.x;
  bool dirty = false;
  for (int c2 = 0; c2 < NCH - 1; c2++) dirty |= (needfix[c2 * 16 + bg] != 0);
  if (!dirty) return;

  __shared__ unsigned short hs[2][16 * 136];
  __shared__ int dns[T_ * 16];

  const int tid = threadIdx.x;
  const int w = tid >> 6;
  const int lane = tid & 63;
  const int l15 = lane & 15;
  const int q = lane >> 4;
  const int bglob = bg * 16 + l15;
  const int kcell = 16 * w + 4 * q;
  const int kq16 = kcell * 4;

  {
    const int* p = done + (size_t)tid * B_ + bg * 16;
    *(int4*)&dns[tid * 16]      = *(const int4*)(p);
    *(int4*)&dns[tid * 16 + 4]  = *(const int4*)(p + 4);
    *(int4*)&dns[tid * 16 + 8]  = *(const int4*)(p + 8);
    *(int4*)&dns[tid * 16 + 12] = *(const int4*)(p + 12);
  }

  bf16x8 wf[4][4];
#pragma unroll
  for (int tI = 0; tI < 4; tI++) {
    const int jg = 16 * (w + 8 * tI) + l15;
#pragma unroll
    for (int kc = 0; kc < 4; kc++) {
      const float* p = Whh + (size_t)jg * H_ + kc * 32 + q * 8;
      float4 u0 = *(const float4*)p;
      float4 u1 = *(const float4*)(p + 4);
      bf16x8 r;
      r[0]=(short)f2bf(u0.x); r[1]=(short)f2bf(u0.y); r[2]=(short)f2bf(u0.z); r[3]=(short)f2bf(u0.w);
      r[4]=(short)f2bf(u1.x); r[5]=(short)f2bf(u1.y); r[6]=(short)f2bf(u1.z); r[7]=(short)f2bf(u1.w);
      wf[tI][kc] = r;
    }
  }

  float c_[4];
  {
    float4 cv = *(const float4*)(c0 + (size_t)bglob * H_ + kcell);
    c_[0] = cv.x; c_[1] = cv.y; c_[2] = cv.z; c_[3] = cv.w;
    const int b = tid >> 5, k = (tid & 31) * 4;
    float4 hv = *(const float4*)(h0 + (size_t)(bg * 16 + b) * H_ + k);
    uint2 hp = {bfpack2(hv.x, hv.y), bfpack2(hv.z, hv.w)};
    *(uint2*)&hs[0][b * 136 + k] = hp;
  }
  int cur = 0;
  __syncthreads();

#pragma unroll 1
  for (int ck = 0; ck < NCH; ck++) {
    const int t0 = ck * LCH;
    bool act = true;

    ushort4 pr[4];
    load_pr(pre2 + ((size_t)t0 * B_ + bglob) * G4_ + kq16, pr);

#pragma unroll 1
    for (int u = 0; u < LCH; u++) {
      const int t = t0 + u;
      const int dn = dns[t * 16 + l15];
      const bool nact = act && (dn == 0);
      if (__ballot(nact) == 0ULL) { act = false; break; }
      act = nact;

      ushort4 prn[4];
      const int un = (u + 1 < LCH) ? u + 1 : LCH - 1;
      load_pr(pre2 + ((size_t)(t0 + un) * B_ + bglob) * G4_ + kq16, prn);

      const unsigned short* hb = hs[cur];
      bf16x8 hf[4];
#pragma unroll
      for (int kc = 0; kc < 4; kc++)
        hf[kc] = *(const bf16x8*)&hb[l15 * 136 + kc * 32 + q * 8];

      f32x4 acc[4];
#pragma unroll
      for (int tI = 0; tI < 4; tI++) acc[tI] = (f32x4){0.f, 0.f, 0.f, 0.f};
#pragma unroll
      for (int tI = 0; tI < 4; tI++)
#pragma unroll
        for (int kc = 0; kc < 4; kc++)
          acc[tI] = __builtin_amdgcn_mfma_f32_16x16x32_bf16(
              wf[tI][kc], hf[kc], acc[tI], 0, 0, 0);

      float hv[4];
#pragma unroll
      for (int r = 0; r < 4; r++) {
        const float iv = acc[0][r] + bf2f(pr[r].x);
        const float fv = acc[1][r] + bf2f(pr[r].y);
        const float gv = acc[2][r] + bf2f(pr[r].z);
        const float ov = acc[3][r] + bf2f(pr[r].w);
        float cc = sigf(fv) * c_[r] + sigf(iv) * tanhf_(gv);
        c_[r] = cc;
        hv[r] = sigf(ov) * tanhf_(cc);
      }
      uint2 hp = {bfpack2(hv[0], hv[1]), bfpack2(hv[2], hv[3])};
      *(uint2*)&hs[cur ^ 1][l15 * 136 + kcell] = hp;
      if (act)
        *(uint2*)&hidden[((size_t)t * B_ + bglob) * H_ + kcell] = hp;
#pragma unroll
      for (int tI = 0; tI < 4; tI++) pr[tI] = prn[tI];
      barrier_lds();
      cur ^= 1;
    }

    if (!act) {
      ushort4 hv = *(const ushort4*)&hfin[((size_t)ck * B_ + bglob) * H_ + kcell];
      float4 cv = *(const float4*)&cfin[((size_t)ck * B_ + bglob) * H_ + kcell];
      c_[0] = cv.x; c_[1] = cv.y; c_[2] = cv.z; c_[3] = cv.w;
      *(ushort4*)&hs[cur][l15 * 136 + kcell] = hv;
    }
    barrier_lds();
  }
}

// ---------------------------------------------------------------------------
// K3: out[T*B][13] = hidden @ [W_pi; W_v]^T + [b_pi; b_v]   (unchanged)
// ---------------------------------------------------------------------------
__global__ __launch_bounds__(256) void k3_head(
    const unsigned short* __restrict__ hidden, const float* __restrict__ Wpi,
    const float* __restrict__ bpi, const float* __restrict__ Wv,
    const float* __restrict__ bv, float* __restrict__ out) {
  __shared__ unsigned short hs3[64 * 136];
  __shared__ float bias_s[16];

  const int tid = threadIdx.x;
  const int w = tid >> 6;
  const int lane = tid & 63;
  const int l15 = lane & 15;
  const int q = lane >> 4;
  const int m0 = blockIdx.x * 64;

  if (tid < 16) bias_s[tid] = (tid < 12) ? bpi[tid] : ((tid == 12) ? bv[0] : 0.f);

  bf16x8 wf3[4];
#pragma unroll
  for (int kc = 0; kc < 4; kc++) {
    float4 u0 = {0.f, 0.f, 0.f, 0.f}, u1 = {0.f, 0.f, 0.f, 0.f};
    if (l15 < 12) {
      const float* p = Wpi + (size_t)l15 * H_ + kc * 32 + q * 8;
      u0 = *(const float4*)p; u1 = *(const float4*)(p + 4);
    } else if (l15 == 12) {
      const float* p = Wv + kc * 32 + q * 8;
      u0 = *(const float4*)p; u1 = *(const float4*)(p + 4);
    }
    bf16x8 r;
    r[0]=(short)f2bf(u0.x); r[1]=(short)f2bf(u0.y); r[2]=(short)f2bf(u0.z); r[3]=(short)f2bf(u0.w);
    r[4]=(short)f2bf(u1.x); r[5]=(short)f2bf(u1.y); r[6]=(short)f2bf(u1.z); r[7]=(short)f2bf(u1.w);
    wf3[kc] = r;
  }

  {
    const int row = tid >> 2, ks = (tid & 3) * 32;
    const unsigned short* p = hidden + (size_t)(m0 + row) * H_ + ks;
#pragma unroll
    for (int i = 0; i < 4; i++)
      *(uint4*)&hs3[row * 136 + ks + i * 8] = *(const uint4*)(p + i * 8);
  }
  __syncthreads();

  f32x4 acc = (f32x4){0.f, 0.f, 0.f, 0.f};
#pragma unroll
  for (int kc = 0; kc < 4; kc++) {
    bf16x8 hf = *(bf16x8*)&hs3[(16 * w + l15) * 136 + kc * 32 + q * 8];
    acc = __builtin_amdgcn_mfma_f32_16x16x32_bf16(wf3[kc], hf, acc, 0, 0, 0);
  }

  const float4 bb = *(float4*)&bias_s[4 * q];
  const int m = m0 + 16 * w + l15;
  const size_t ro = (size_t)m * 13;
  float v0 = acc[0] + bb.x, v1 = acc[1] + bb.y, v2 = acc[2] + bb.z, v3 = acc[3] + bb.w;
  if (q < 3) {
    out[ro + 4 * q + 0] = v0;
    out[ro + 4 * q + 1] = v1;
    out[ro + 4 * q + 2] = v2;
    out[ro + 4 * q + 3] = v3;
  } else {
    out[ro + 12] = v0;
  }
}

// ---------------------------------------------------------------------------
// Workspace (ws, 167.8 MB):
//   pre2   bf16 [131072][512] @ 0            (cell-major-quad layout)
//   hidden bf16 [131072][128] @ 134,217,728
// Scratch in d_out (6.5 MB, overwritten by K3 at the end):
//   Wb2 bf16 [512][320] @ 0 (320 KB)   bias2 fp32 [512] @ 512 KB
//   hfin @ 1 MB, cfin @ 2 MB, needfix @ 4 MB
// ---------------------------------------------------------------------------
extern "C" void kernel_launch(void* const* d_in, const int* in_sizes, int n_in,
                              void* d_out, int out_size, void* d_ws, size_t ws_size,
                              hipStream_t stream) {
  const float* x    = (const float*)d_in[0];
  const int* done   = (const int*)d_in[1];
  const float* h0   = (const float*)d_in[2];
  const float* c0   = (const float*)d_in[3];
  const float* Wih  = (const float*)d_in[4];
  const float* Whh  = (const float*)d_in[5];
  const float* bih  = (const float*)d_in[6];
  const float* bhh  = (const float*)d_in[7];
  const float* Wpi  = (const float*)d_in[8];
  const float* bpi  = (const float*)d_in[9];
  const float* Wv   = (const float*)d_in[10];
  const float* bv   = (const float*)d_in[11];
  (void)in_sizes; (void)n_in; (void)out_size; (void)ws_size;

  unsigned short* pre2 = (unsigned short*)d_ws;
  unsigned short* hidden = pre2 + (size_t)TB_ * G4_;
  unsigned short* Wb   = (unsigned short*)d_out;
  float* bias2         = (float*)((char*)d_out + (512u << 10));
  unsigned short* hfin = (unsigned short*)((char*)d_out + (1u << 20));
  float* cfin          = (float*)((char*)d_out + (2u << 20));
  int* needfix         = (int*)((char*)d_out + (4u << 20));
  float* out = (float*)d_out;

  k0w_cvt<<<80, 256, 0, stream>>>(Wih, bih, bhh, Wb, bias2);
  k1_pregemm<<<TB_ / 128, 512, 0, stream>>>(x, Wb, bias2, pre2);
  k2a_chunk<<<256, 512, 0, stream>>>(pre2, Whh, done, hidden, hfin, cfin);
  k2b_par<<<256, 512, 0, stream>>>(pre2, Whh, h0, c0, done, hidden, hfin, cfin, needfix);
  k2c_guard<<<16, 512, 0, stream>>>(pre2, Whh, h0, c0, done, hidden, hfin, cfin, needfix);
  k3_head<<<TB_ / 64, 256, 0, stream>>>(hidden, Wpi, bpi, Wv, bv, out);
}